// Round 5
// baseline (610.093 us; speedup 1.0000x reference)
//
#include <hip/hip_runtime.h>
#include <hip/hip_bf16.h>
#include <hip/hip_cooperative_groups.h>

namespace cg = cooperative_groups;

typedef unsigned short u16;
typedef unsigned int u32;
typedef __bf16 bf16x8 __attribute__((ext_vector_type(8)));
typedef float f32x4 __attribute__((ext_vector_type(4)));

#define DIM 128

__device__ __forceinline__ u16 f2bf_rne(float x) {
  u32 u = __float_as_uint(x);
  return (u16)((u + 0x7fffu + ((u >> 16) & 1u)) >> 16);
}
__device__ __forceinline__ u32 packbf2(float x, float y) {
  return (u32)f2bf_rne(x) | ((u32)f2bf_rne(y) << 16);
}
__device__ __forceinline__ float lrelu(float x) { return x > 0.f ? x : 0.01f * x; }
__device__ __forceinline__ int iclamp(int v, int hi) { return v < 0 ? 0 : (v >= hi ? hi - 1 : v); }
__device__ __forceinline__ float sane(float x) { return (x == x) ? x : 0.f; }

__device__ __forceinline__ float wred_max(float v) {
  #pragma unroll
  for (int o = 32; o > 0; o >>= 1) v = fmaxf(v, __shfl_xor(v, o, 64));
  return v;
}
__device__ __forceinline__ float wred_sum(float v) {
  #pragma unroll
  for (int o = 32; o > 0; o >>= 1) v += __shfl_xor(v, o, 64);
  return v;
}

// ================= args =================
struct MegaArgs {
  const float* W1[3]; const float* Wmod[3]; int K[3];
  const float* rel; const float* b1[3]; const float* bmod[3]; const float* w2[3];
  const float* A[3];
  const int* dst; const int* src; const int* etyp;
  const float* alphaP; const float* gammaP;
  u16* Wc[3]; u16* PrAll; u16* PdAll; u16* PsAll;
  float* qr[3]; float* qd[3]; float* qs[3];
  int* cnt; int* rank; int* offs; int* partial; u32* sortedST;
  float* outp;
  int E; int N; int NR;
  int z0Tot;
  int wc2End; int wc1End; int wc0End; int aCompute; int aTot;
  int tilesPerM; int cGemm; int cTot;
  int dTot;
};

// ---------------- phase A: WC build + PR prep + hist/rank ----------------
__device__ __forceinline__ void phaseA(const MegaArgs& a, int vb, void* lds) {
  int tid = threadIdx.x;
  if (vb >= a.aCompute) {
    // hist + rank (atomic returns stable per-node rank)
    int e = (vb - a.aCompute) * 256 + tid;
    if (e < a.E) {
      int d = a.dst[e];
      if (d >= 0 && d < a.N) a.rank[e] = atomicAdd(&a.cnt[d], 1);
    }
    return;
  }
  if (vb < a.wc0End) {
    // Wc build: Wc[m] = W1half @ Wmod (bf16, PACKED trip-major)
    int m, loc;
    if (vb < a.wc2End)      { m = 2; loc = vb; }
    else if (vb < a.wc1End) { m = 1; loc = vb - a.wc2End; }
    else                    { m = 0; loc = vb - a.wc1End; }
    int o = loc & 255, kb = loc >> 8;
    int k = (kb << 8) + tid;
    int K = a.K[m];
    if (k < K) {
      int halfsel = (o >= 128) ? 128 : 0;
      int oo = o & 127;
      const float* W1 = a.W1[m];
      const float* Wm = a.Wmod[m];
      float acc;
      if (Wm == nullptr) {
        acc = W1[oo * 384 + halfsel + k];
      } else {
        acc = 0.f;
        for (int i = 0; i < 128; ++i)
          acc += W1[oo * 384 + halfsel + i] * Wm[i * K + k];
      }
      a.Wc[m][((size_t)(k >> 5) * 256 + o) * 32 + (k & 31)] = f2bf_rne(acc);
    }
    return;
  }
  // relation prep (2 r per virtual block)
  float* red = (float*)lds;
  int idx = vb - a.wc0End;
  int NRpair = (a.NR + 1) >> 1;
  int m = idx / NRpair;
  if (m > 2) return;
  int rp = idx - m * NRpair;
  int half = tid >> 7, o = tid & 127;
  int r = rp * 2 + half;
  bool ok = (r < a.NR);
  float acc = 0.f;
  if (ok) {
    const float* W1 = a.W1[m];
    acc = a.b1[m][o];
    for (int i = 0; i < 128; ++i)
      acc += W1[o * 384 + 256 + i] * a.rel[r * 128 + i];
    const float* bmod = a.bmod[m];
    if (bmod != nullptr) {
      for (int i = 0; i < 128; ++i)
        acc += (W1[o * 384 + i] + W1[o * 384 + 128 + i]) * bmod[i];
    }
    a.PrAll[(size_t)r * 384 + m * 128 + o] = f2bf_rne(acc);
  }
  red[tid] = ok ? acc * a.w2[m][o] : 0.f;
  __syncthreads();
  int base = half << 7;
  for (int s = 64; s > 0; s >>= 1) {
    if (o < s) red[base + o] += red[base + o + s];
    __syncthreads();
  }
  if (o == 0 && ok) a.qr[m][r] = sane(red[base]);
  __syncthreads();   // protect LDS reuse across persistent-loop iterations
}

// ---------------- distributed scan (3 sub-phases, grid.sync between) ------
__device__ __forceinline__ void scanB1(const MegaArgs& a, int b, int gsz, void* lds) {
  int* sums = (int*)lds;
  int t = threadIdx.x;
  int chunk = (a.N + gsz - 1) / gsz;
  int base = b * chunk;
  int perT = (chunk + 255) >> 8;
  int s = 0;
  for (int i = 0; i < perT; ++i) {
    int idx = base + t * perT + i;
    if (idx < base + chunk && idx < a.N) s += a.cnt[idx];
  }
  sums[t] = s;
  __syncthreads();
  for (int off = 1; off < 256; off <<= 1) {
    int v = (t >= off) ? sums[t - off] : 0;
    __syncthreads();
    sums[t] += v;
    __syncthreads();
  }
  if (t == 255) a.partial[b] = sums[255];
  __syncthreads();
}

__device__ __forceinline__ void scanB2(const MegaArgs& a, int gsz, void* lds) {
  int* sums = (int*)lds;
  int t = threadIdx.x;
  int G = (gsz + 255) >> 8;
  int s = 0;
  for (int i = 0; i < G; ++i) {
    int idx = t * G + i;
    if (idx < gsz) s += a.partial[idx];
  }
  sums[t] = s;
  __syncthreads();
  for (int off = 1; off < 256; off <<= 1) {
    int v = (t >= off) ? sums[t - off] : 0;
    __syncthreads();
    sums[t] += v;
    __syncthreads();
  }
  if (t == 255) a.offs[a.N] = sums[255];
  int pre = (t > 0) ? sums[t - 1] : 0;
  for (int i = 0; i < G; ++i) {
    int idx = t * G + i;
    if (idx < gsz) { int c = a.partial[idx]; a.partial[idx] = pre; pre += c; }
  }
  __syncthreads();
}

__device__ __forceinline__ void scanB3(const MegaArgs& a, int b, int gsz, void* lds) {
  int* sums = (int*)lds;
  int t = threadIdx.x;
  int chunk = (a.N + gsz - 1) / gsz;
  int base = b * chunk;
  int perT = (chunk + 255) >> 8;
  int s = 0;
  for (int i = 0; i < perT; ++i) {
    int idx = base + t * perT + i;
    if (idx < base + chunk && idx < a.N) s += a.cnt[idx];
  }
  sums[t] = s;
  __syncthreads();
  for (int off = 1; off < 256; off <<= 1) {
    int v = (t >= off) ? sums[t - off] : 0;
    __syncthreads();
    sums[t] += v;
    __syncthreads();
  }
  int prefix = a.partial[b] + ((t > 0) ? sums[t - 1] : 0);
  for (int i = 0; i < perT; ++i) {
    int idx = base + t * perT + i;
    if (idx < base + chunk && idx < a.N) { a.offs[idx] = prefix; prefix += a.cnt[idx]; }
  }
  __syncthreads();
}

// ---------------- gemm, 16-row tiles, full K staged once, 1 barrier ------
// LDS [kb][16 rows][32 k] u16; 16B-group XOR swizzle g ^= (row&3) ^ (kb&3)
// (write: 64 lanes cover 512 B uniformly = bank minimum; read: ds_read_b128
//  over 16 rows x 4 groups, uniform = minimum).
// C/D layout (verified rounds 0-3): col = lane&15, row = (lane>>4)*4 + reg
__device__ __forceinline__ void stash16(u16* Als, int srow, int tk4, int i, float4 v) {
  int kb = 2 * i + (tk4 >> 5);
  int kl = tk4 & 31;
  int gidx = (kl >> 3) ^ (srow & 3) ^ (kb & 3);
  u32* dp = reinterpret_cast<u32*>(&Als[(kb * 16 + srow) * 32 + (gidx << 3) + (kl & 7)]);
  dp[0] = packbf2(v.x, v.y);
  dp[1] = packbf2(v.z, v.w);
}

__device__ __forceinline__ void epilogue16(const MegaArgs& g, int m, int row0,
                                           f32x4 (&acc)[4], float (*qpart)[16]) {
  int tid = threadIdx.x;
  int lane = tid & 63, wv = tid >> 6;
  int quad = lane >> 4, l16 = lane & 15;
  const float* w2 = g.w2[m];
  float w2c[4];
  #pragma unroll
  for (int t = 0; t < 4; ++t) w2c[t] = w2[(wv & 1) * 64 + t * 16 + l16];
  float part[4];
  #pragma unroll
  for (int r = 0; r < 4; ++r) {
    int rr = row0 + quad * 4 + r;
    bool ok = rr < g.N;
    float qp = 0.f;
    #pragma unroll
    for (int t = 0; t < 4; ++t) {
      int cc = (wv & 1) * 64 + t * 16 + l16;
      if (ok) {
        if (wv < 2) g.PdAll[(size_t)rr * 384 + m * 128 + cc] = f2bf_rne(acc[t][r]);
        else        g.PsAll[(size_t)rr * 384 + m * 128 + cc] = f2bf_rne(acc[t][r]);
      }
      qp += acc[t][r] * w2c[t];
    }
    #pragma unroll
    for (int mk = 1; mk < 16; mk <<= 1) qp += __shfl_xor(qp, mk, 64);
    part[r] = qp;
  }
  if (l16 == 0) {
    #pragma unroll
    for (int r = 0; r < 4; ++r) qpart[wv][quad * 4 + r] = part[r];
  }
  __syncthreads();
  if (tid < 32) {
    int row = tid & 15, half = tid >> 4;
    int rr = row0 + row;
    if (rr < g.N) {
      if (half == 0) g.qd[m][rr] = sane(qpart[0][row] + qpart[1][row]);
      else           g.qs[m][rr] = sane(qpart[2][row] + qpart[3][row]);
    }
  }
  __syncthreads();   // protect qpart reuse across persistent-loop iterations
}

template<int NT>
__device__ __forceinline__ void gemm16(const MegaArgs& g, int m, int tile,
                                       u16* Als, float (*qpart)[16]) {
  constexpr int NS = NT / 2;           // float4 steps per thread (64 k per step)
  constexpr int H = (NS + 1) / 2;
  int tid = threadIdx.x;
  int lane = tid & 63, wv = tid >> 6;
  int quad = lane >> 4, l16 = lane & 15;
  int row0 = tile * 16;
  int srow = tid >> 4;                 // 0..15
  int tk4 = (tid & 15) * 4;            // 0..60 (f32 col units within 64-k step)
  int grow = row0 + srow;
  if (grow >= g.N) grow = g.N - 1;     // dup loads; stores guarded
  const float* Ag = g.A[m] + (size_t)grow * (NT * 32);

  float4 vreg[H];
  #pragma unroll
  for (int i = 0; i < H; ++i) vreg[i] = *reinterpret_cast<const float4*>(Ag + tk4 + i * 64);
  #pragma unroll
  for (int i = 0; i < H; ++i) stash16(Als, srow, tk4, i, vreg[i]);
  #pragma unroll
  for (int i = H; i < NS; ++i) vreg[i - H] = *reinterpret_cast<const float4*>(Ag + tk4 + i * 64);
  #pragma unroll
  for (int i = H; i < NS; ++i) stash16(Als, srow, tk4, i, vreg[i - H]);
  __syncthreads();

  const u16* Bpg = g.Wc[m] + (size_t)(wv * 64 + l16) * 32 + quad * 8;
  f32x4 acc[4];
  #pragma unroll
  for (int t = 0; t < 4; ++t) acc[t] = (f32x4){0.f, 0.f, 0.f, 0.f};

  #pragma unroll
  for (int kb = 0; kb < NT; ++kb) {
    const u16* bp = Bpg + (size_t)kb * 8192;
    bf16x8 b0 = *reinterpret_cast<const bf16x8*>(bp);
    bf16x8 b1 = *reinterpret_cast<const bf16x8*>(bp + 512);
    bf16x8 b2 = *reinterpret_cast<const bf16x8*>(bp + 1024);
    bf16x8 b3 = *reinterpret_cast<const bf16x8*>(bp + 1536);
    int gsw = (quad ^ (l16 & 3) ^ (kb & 3)) << 3;
    bf16x8 av = *reinterpret_cast<const bf16x8*>(&Als[(kb * 16 + l16) * 32 + gsw]);
    acc[0] = __builtin_amdgcn_mfma_f32_16x16x32_bf16(av, b0, acc[0], 0, 0, 0);
    acc[1] = __builtin_amdgcn_mfma_f32_16x16x32_bf16(av, b1, acc[1], 0, 0, 0);
    acc[2] = __builtin_amdgcn_mfma_f32_16x16x32_bf16(av, b2, acc[2], 0, 0, 0);
    acc[3] = __builtin_amdgcn_mfma_f32_16x16x32_bf16(av, b3, acc[3], 0, 0, 0);
  }
  epilogue16(g, m, row0, acc, qpart);
}

// generic-K fallback (chunked, 2 barriers per chunk)
__device__ void gemm16_gen(const MegaArgs& g, int m, int tile,
                           u16* Als, float (*qpart)[16]) {
  const int K = g.K[m];
  int nt = K >> 5;
  int tid = threadIdx.x;
  int lane = tid & 63, wv = tid >> 6;
  int quad = lane >> 4, l16 = lane & 15;
  int row0 = tile * 16;
  int srow = tid >> 4;
  int tk4 = (tid & 15) * 4;
  int grow = row0 + srow;
  if (grow >= g.N) grow = g.N - 1;
  const float* Ag = g.A[m] + (size_t)grow * K;
  const u16* Bpg = g.Wc[m] + (size_t)(wv * 64 + l16) * 32 + quad * 8;
  f32x4 acc[4];
  #pragma unroll
  for (int t = 0; t < 4; ++t) acc[t] = (f32x4){0.f, 0.f, 0.f, 0.f};
  for (int c0 = 0; c0 < nt; c0 += 24) {
    int kc = nt - c0; if (kc > 24) kc = 24;
    __syncthreads();
    for (int i = 0; i < (kc + 1) / 2; ++i) {
      int kg = c0 * 32 + tk4 + i * 64;
      if (kg + 3 < K) {
        float4 v = *reinterpret_cast<const float4*>(Ag + kg);
        stash16(Als, srow, tk4, i, v);
      }
    }
    __syncthreads();
    for (int kb = 0; kb < kc; ++kb) {
      const u16* bp = Bpg + (size_t)(c0 + kb) * 8192;
      bf16x8 b0 = *reinterpret_cast<const bf16x8*>(bp);
      bf16x8 b1 = *reinterpret_cast<const bf16x8*>(bp + 512);
      bf16x8 b2 = *reinterpret_cast<const bf16x8*>(bp + 1024);
      bf16x8 b3 = *reinterpret_cast<const bf16x8*>(bp + 1536);
      int gsw = (quad ^ (l16 & 3) ^ (kb & 3)) << 3;
      bf16x8 av = *reinterpret_cast<const bf16x8*>(&Als[(kb * 16 + l16) * 32 + gsw]);
      acc[0] = __builtin_amdgcn_mfma_f32_16x16x32_bf16(av, b0, acc[0], 0, 0, 0);
      acc[1] = __builtin_amdgcn_mfma_f32_16x16x32_bf16(av, b1, acc[1], 0, 0, 0);
      acc[2] = __builtin_amdgcn_mfma_f32_16x16x32_bf16(av, b2, acc[2], 0, 0, 0);
      acc[3] = __builtin_amdgcn_mfma_f32_16x16x32_bf16(av, b3, acc[3], 0, 0, 0);
    }
  }
  epilogue16(g, m, row0, acc, qpart);
}

// ---------------- phase C: gemm | atomic-free scatter ----------------
__device__ __forceinline__ void phaseC(const MegaArgs& a, int vb,
                                       u16* Als, float (*qpart)[16]) {
  if (vb >= a.cGemm) {
    int e = (vb - a.cGemm) * 256 + threadIdx.x;
    if (e < a.E) {
      int d = a.dst[e];
      if (d >= 0 && d < a.N) {
        int pos = a.offs[d] + a.rank[e];
        if (pos >= 0 && pos < a.E) {
          u32 s = (u32)iclamp(a.src[e], a.N);
          u32 t = (u32)iclamp(a.etyp[e], a.NR);
          a.sortedST[pos] = (t << 16) | s;
        }
      }
    }
    return;
  }
  int tpm = a.tilesPerM;
  int m, tile;
  if (vb < tpm)            { m = 2; tile = vb; }
  else if (vb < 2 * tpm)   { m = 1; tile = vb - tpm; }
  else                     { m = 0; tile = vb - 2 * tpm; }
  int K = a.K[m];
  if (K == 768)      gemm16<24>(a, m, tile, Als, qpart);
  else if (K == 512) gemm16<16>(a, m, tile, Als, qpart);
  else if (K == 128) gemm16<4>(a, m, tile, Als, qpart);
  else               gemm16_gen(a, m, tile, Als, qpart);
}

// ---------------- phase D: fused 3-modality online-softmax aggregate ------
__device__ void phaseD(const MegaArgs& a, int vb) {
  int n = vb * 4 + (threadIdx.x >> 6);
  if (n >= a.N) return;
  int lane = threadIdx.x & 63;
  int E = a.E;
  int eb = a.offs[n], ee = a.offs[n + 1];
  if (eb < 0) eb = 0;
  if (eb > E) eb = E;
  if (ee < eb) ee = eb;
  if (ee > E) ee = E;
  int En = ee - eb;

  float al = a.alphaP[0];
  if (!(al > 0.f && al < 1.f)) al = 0.1f;
  float ga = a.gammaP[0];
  if (!(ga > 0.f && ga < 1.f)) ga = 0.8f;
  float coef[3] = {1.f - al - ga, al, ga};

  float qdn[3];
  #pragma unroll
  for (int m = 0; m < 3; ++m) qdn[m] = sane(a.qd[m][n]);

  const u16* PsAll = a.PsAll;
  const u16* PrAll = a.PrAll;
  int dlo = 2 * lane;

  float rm[3] = {-1e30f, -1e30f, -1e30f};
  float z[3] = {0.f, 0.f, 0.f};
  float a0[3] = {0.f, 0.f, 0.f};
  float a1[3] = {0.f, 0.f, 0.f};
  for (int c0 = 0; c0 < En; c0 += 64) {
    int cn = min(64, En - c0);
    u32 stp = 0;
    float bm[3] = {-1e30f, -1e30f, -1e30f};
    if (lane < cn) {
      stp = a.sortedST[eb + c0 + lane];
      int s = (int)(stp & 0xffffu);
      int t = (int)(stp >> 16);
      #pragma unroll
      for (int m = 0; m < 3; ++m)
        bm[m] = lrelu(qdn[m] + a.qs[m][s] + a.qr[m][t]);
    }
    float wr[3];
    #pragma unroll
    for (int m = 0; m < 3; ++m) {
      float cm = wred_max(bm[m]);
      float nm = fmaxf(rm[m], cm);
      float sc = __expf(fmaxf(rm[m] - nm, -80.f));
      z[m] *= sc; a0[m] *= sc; a1[m] *= sc;
      rm[m] = nm;
      wr[m] = (lane < cn) ? __expf(fmaxf(bm[m] - nm, -80.f)) : 0.f;
      z[m] += wr[m];
    }

    int cnR = (cn + 3) & ~3;
    for (int j = 0; j < cnR; j += 4) {
      u32 stj[4];
      float wj[4][3];
      #pragma unroll
      for (int u = 0; u < 4; ++u) {
        stj[u] = __shfl(stp, j + u, 64);
        wj[u][0] = __shfl(wr[0], j + u, 64);
        wj[u][1] = __shfl(wr[1], j + u, 64);
        wj[u][2] = __shfl(wr[2], j + u, 64);
      }
      u32 pu[4][3], ru[4][3];
      #pragma unroll
      for (int u = 0; u < 4; ++u) {
        const u16* ps = PsAll + (size_t)(stj[u] & 0xffffu) * 384 + dlo;
        const u16* pr = PrAll + (size_t)(stj[u] >> 16) * 384 + dlo;
        #pragma unroll
        for (int m = 0; m < 3; ++m) {
          pu[u][m] = *reinterpret_cast<const u32*>(ps + m * 128);
          ru[u][m] = *reinterpret_cast<const u32*>(pr + m * 128);
        }
      }
      #pragma unroll
      for (int u = 0; u < 4; ++u) {
        #pragma unroll
        for (int m = 0; m < 3; ++m) {
          float ps0 = __uint_as_float(pu[u][m] << 16);
          float ps1 = __uint_as_float(pu[u][m] & 0xffff0000u);
          float pr0 = __uint_as_float(ru[u][m] << 16);
          float pr1 = __uint_as_float(ru[u][m] & 0xffff0000u);
          a0[m] = fmaf(wj[u][m], ps0 + pr0, a0[m]);
          a1[m] = fmaf(wj[u][m], ps1 + pr1, a1[m]);
        }
      }
    }
  }
  #pragma unroll
  for (int m = 0; m < 3; ++m) z[m] = wred_sum(z[m]);

  float o0 = 0.f, o1 = 0.f;
  const u16* pd = a.PdAll + (size_t)n * 384 + dlo;
  #pragma unroll
  for (int m = 0; m < 3; ++m) {
    float h0 = 0.f, h1 = 0.f;
    if (En > 0 && z[m] > 0.f) {
      float rz = 1.f / z[m];
      u32 du = *reinterpret_cast<const u32*>(pd + m * 128);
      float pd0 = __uint_as_float(du << 16), pd1 = __uint_as_float(du & 0xffff0000u);
      h0 = lrelu(pd0 + a0[m] * rz);
      h1 = lrelu(pd1 + a1[m] * rz);
    }
    o0 = fmaf(coef[m], h0, o0);
    o1 = fmaf(coef[m], h1, o1);
  }
  float* op = a.outp + (size_t)n * 128 + dlo;
  op[0] = sane(o0);
  op[1] = sane(o1);
}

// ================= the cooperative mega-kernel =================
__global__ __launch_bounds__(256) void mega_kernel(MegaArgs a) {
  cg::grid_group grid = cg::this_grid();
  __shared__ __align__(16) u16 Als[24 * 16 * 32];   // 24 KB, reused by all phases
  __shared__ float qpart[4][16];
  int gsz = gridDim.x, b0 = blockIdx.x;

  // A0: zero counts
  for (int vb = b0; vb < a.z0Tot; vb += gsz) {
    int i = vb * 256 + threadIdx.x;
    if (i < a.N) a.cnt[i] = 0;
  }
  grid.sync();
  // A: WC + PR + hist/rank
  for (int vb = b0; vb < a.aTot; vb += gsz) phaseA(a, vb, Als);
  grid.sync();
  // B: distributed exclusive scan counts -> offs
  scanB1(a, b0, gsz, Als);
  grid.sync();
  if (b0 == 0) scanB2(a, gsz, Als);
  grid.sync();
  scanB3(a, b0, gsz, Als);
  grid.sync();
  // C: gemm + scatter
  for (int vb = b0; vb < a.cTot; vb += gsz) phaseC(a, vb, Als, qpart);
  grid.sync();
  // D: aggregate
  for (int vb = b0; vb < a.dTot; vb += gsz) phaseD(a, vb);
}

// ================= non-cooperative fallback path =================
__global__ __launch_bounds__(256) void fb_prep(MegaArgs a) {
  __shared__ __align__(16) float red[256];
  phaseA(a, blockIdx.x, red);
}
__global__ __launch_bounds__(1024) void fb_scan(const int* __restrict__ cnt,
                                                int* __restrict__ offs, int N) {
  __shared__ int sums[1024];
  int t = threadIdx.x;
  int chunk = (N + 1023) >> 10;
  int base = t * chunk;
  int s = 0;
  for (int i = 0; i < chunk; ++i) { int idx = base + i; if (idx < N) s += cnt[idx]; }
  sums[t] = s;
  __syncthreads();
  for (int off = 1; off < 1024; off <<= 1) {
    int v = (t >= off) ? sums[t - off] : 0;
    __syncthreads();
    sums[t] += v;
    __syncthreads();
  }
  int prefix = (t > 0) ? sums[t - 1] : 0;
  for (int i = 0; i < chunk; ++i) {
    int idx = base + i;
    if (idx < N) { offs[idx] = prefix; prefix += cnt[idx]; }
  }
  if (t == 1023) offs[N] = sums[1023];
}
__global__ __launch_bounds__(256) void fb_main(MegaArgs a) {
  __shared__ __align__(16) u16 Als[24 * 16 * 32];
  __shared__ float qpart[4][16];
  phaseC(a, blockIdx.x, Als, qpart);
}
__global__ __launch_bounds__(256) void fb_agg(MegaArgs a) {
  phaseD(a, blockIdx.x);
}

extern "C" void kernel_launch(void* const* d_in, const int* in_sizes, int n_in,
                              void* d_out, int out_size, void* d_ws, size_t ws_size,
                              hipStream_t stream) {
  const int* ei        = (const int*)d_in[1];
  const int* et        = (const int*)d_in[2];
  const float* visual  = (const float*)d_in[3];
  const float* textual = (const float*)d_in[4];
  const float* semb    = (const float*)d_in[5];
  const float* relemb  = (const float*)d_in[6];
  const float* W1s = (const float*)d_in[7];
  const float* b1s = (const float*)d_in[8];
  const float* w2s = (const float*)d_in[9];
  const float* W1v = (const float*)d_in[10];
  const float* b1v = (const float*)d_in[11];
  const float* w2v = (const float*)d_in[12];
  const float* W1t = (const float*)d_in[13];
  const float* b1t = (const float*)d_in[14];
  const float* w2t = (const float*)d_in[15];
  const float* Wv  = (const float*)d_in[16];
  const float* bv  = (const float*)d_in[17];
  const float* Wt  = (const float*)d_in[18];
  const float* bt  = (const float*)d_in[19];
  const float* alphaP = (const float*)d_in[20];
  const float* gammaP = (const float*)d_in[21];
  float* outp = (float*)d_out;

  const int E   = in_sizes[2];
  const int N   = in_sizes[5] / DIM;
  const int NR  = in_sizes[6] / DIM;
  const int VIS = in_sizes[3] / N;   // 512
  const int TXT = in_sizes[4] / N;   // 768
  int Ks[3] = {DIM, VIS, TXT};

  const float* W1a[3]   = {W1s, W1v, W1t};
  const float* b1a[3]   = {b1s, b1v, b1t};
  const float* w2a[3]   = {w2s, w2v, w2t};
  const float* Wmoda[3] = {nullptr, Wv, Wt};
  const float* bmoda[3] = {nullptr, bv, bt};
  const float* Amoda[3] = {semb, visual, textual};

  const int* esrc = ei;
  const int* edst = ei + E;
  int egrid = (E + 255) / 256;

  size_t off = 0;
  auto take = [&](size_t bytes) -> size_t {
    size_t o = off;
    off = (off + bytes + 255) & ~(size_t)255;
    return o;
  };
  size_t o_cnt  = take((size_t)N * 4);
  size_t o_rank = take((size_t)E * 4);
  size_t o_offs = take((size_t)(N + 1) * 4);
  size_t o_part = take((size_t)4096 * 4);
  size_t o_st   = take((size_t)E * 4);
  size_t o_qdm[3], o_qsm[3], o_qrm[3], o_Wcm[3];
  for (int m = 0; m < 3; ++m) {
    o_qdm[m] = take((size_t)N * 4);
    o_qsm[m] = take((size_t)N * 4);
    o_qrm[m] = take((size_t)NR * 4);
    o_Wcm[m] = take((size_t)256 * Ks[m] * 2);
  }
  size_t o_PrAll = take((size_t)NR * 384 * 2);
  size_t o_PdAll = take((size_t)N * 384 * 2);
  size_t o_PsAll = take((size_t)N * 384 * 2);
  size_t need = off;                           // ~19 MB

  if (ws_size < need) {
    (void)hipMemsetAsync(d_out, 0, (size_t)out_size * 4, stream);  // finite diagnostic
    return;
  }

  char* w = (char*)d_ws;

  MegaArgs ma;
  ma.rel = relemb; ma.NR = NR; ma.E = E; ma.N = N;
  ma.dst = edst; ma.src = esrc; ma.etyp = et;
  ma.alphaP = alphaP; ma.gammaP = gammaP;
  ma.PrAll = (u16*)(w + o_PrAll);
  ma.PdAll = (u16*)(w + o_PdAll);
  ma.PsAll = (u16*)(w + o_PsAll);
  ma.cnt = (int*)(w + o_cnt);
  ma.rank = (int*)(w + o_rank);
  ma.offs = (int*)(w + o_offs);
  ma.partial = (int*)(w + o_part);
  ma.sortedST = (u32*)(w + o_st);
  ma.outp = outp;
  for (int m = 0; m < 3; ++m) {
    ma.W1[m] = W1a[m]; ma.Wmod[m] = Wmoda[m]; ma.K[m] = Ks[m];
    ma.b1[m] = b1a[m]; ma.bmod[m] = bmoda[m]; ma.w2[m] = w2a[m];
    ma.A[m] = Amoda[m];
    ma.Wc[m] = (u16*)(w + o_Wcm[m]);
    ma.qr[m] = (float*)(w + o_qrm[m]);
    ma.qd[m] = (float*)(w + o_qdm[m]);
    ma.qs[m] = (float*)(w + o_qsm[m]);
  }
  int kbm[3];
  for (int m = 0; m < 3; ++m) kbm[m] = (Ks[m] + 255) / 256;
  int NRpair = (NR + 1) / 2;
  ma.z0Tot  = (N + 255) / 256;
  ma.wc2End = 256 * kbm[2];
  ma.wc1End = ma.wc2End + 256 * kbm[1];
  ma.wc0End = ma.wc1End + 256 * kbm[0];
  ma.aCompute = ma.wc0End + 3 * NRpair;
  ma.aTot   = ma.aCompute + egrid;
  ma.tilesPerM = (N + 15) / 16;
  ma.cGemm  = 3 * ma.tilesPerM;
  ma.cTot   = ma.cGemm + egrid;
  ma.dTot   = (N + 3) / 4;

  // ---- cooperative capability + grid sizing (cached) ----
  static int s_coop = -1;
  static int s_grid = 1024;
  if (s_coop < 0) {
    int dev = 0;
    (void)hipGetDevice(&dev);
    int coop = 0;
    (void)hipDeviceGetAttribute(&coop, hipDeviceAttributeCooperativeLaunch, dev);
    int nCU = 256;
    (void)hipDeviceGetAttribute(&nCU, hipDeviceAttributeMultiprocessorCount, dev);
    int bpc = 0;
    hipError_t oe = hipOccupancyMaxActiveBlocksPerMultiprocessor(&bpc, mega_kernel, 256, 0);
    if (oe != hipSuccess || bpc <= 0) bpc = 2;   // conservative, guaranteed co-resident
    long g = (long)nCU * bpc;
    if (g > 4096) g = 4096;                      // partial[] capacity
    if (g < 64) g = 64;
    s_grid = (int)g;
    s_coop = coop;
  }

  if (s_coop) {
    // cascade: if the occupancy-derived grid is too large for co-residency,
    // halve until the cooperative launch is accepted.
    for (int gtry = s_grid; gtry >= 64; gtry >>= 1) {
      void* kargs[] = { (void*)&ma };
      hipError_t le = hipLaunchCooperativeKernel(mega_kernel, dim3(gtry), dim3(256),
                                                 kargs, 0, stream);
      if (le == hipSuccess) {
        s_grid = gtry;          // remember the accepted size
        return;
      }
    }
  }

  // ---- fallback: non-cooperative 4-dispatch pipeline ----
  (void)hipMemsetAsync(ma.cnt, 0, (size_t)N * 4, stream);
  fb_prep<<<ma.aTot, 256, 0, stream>>>(ma);
  fb_scan<<<1, 1024, 0, stream>>>(ma.cnt, ma.offs, N);
  fb_main<<<ma.cTot, 256, 0, stream>>>(ma);
  fb_agg<<<ma.dTot, 256, 0, stream>>>(ma);
}

// Round 6
// 270.520 us; speedup vs baseline: 2.2553x; 2.2553x over previous
//
#include <hip/hip_runtime.h>
#include <hip/hip_bf16.h>

typedef unsigned short u16;
typedef unsigned int u32;
typedef __bf16 bf16x8 __attribute__((ext_vector_type(8)));
typedef float f32x4 __attribute__((ext_vector_type(4)));

#define DIM 128

__device__ __forceinline__ u16 f2bf_rne(float x) {
  u32 u = __float_as_uint(x);
  return (u16)((u + 0x7fffu + ((u >> 16) & 1u)) >> 16);
}
__device__ __forceinline__ u32 packbf2(float x, float y) {
  return (u32)f2bf_rne(x) | ((u32)f2bf_rne(y) << 16);
}
__device__ __forceinline__ float lrelu(float x) { return x > 0.f ? x : 0.01f * x; }
__device__ __forceinline__ int iclamp(int v, int hi) { return v < 0 ? 0 : (v >= hi ? hi - 1 : v); }
__device__ __forceinline__ float sane(float x) { return (x == x) ? x : 0.f; }

__device__ __forceinline__ float wred_max(float v) {
  #pragma unroll
  for (int o = 32; o > 0; o >>= 1) v = fmaxf(v, __shfl_xor(v, o, 64));
  return v;
}
__device__ __forceinline__ float wred_sum(float v) {
  #pragma unroll
  for (int o = 32; o > 0; o >>= 1) v += __shfl_xor(v, o, 64);
  return v;
}

// ================= structs =================
struct PrepAllArgs {
  const float* W1[3]; const float* Wmod[3]; int K[3]; u16* Wc[3];
  const float* rel; const float* b1[3]; const float* bmod[3]; const float* w2[3];
  u16* PrAll; float* qr[3]; int NR;
  const int* dst; int* cnt; int* rank; int E; int N;
  int wc2End; int wc1End; int wc0End; int nCompute; int totB;
};
struct MainArgs {
  const float* A[3]; const u16* B[3]; const float* w2[3];
  u16* PdAll; u16* PsAll; float* qd[3]; float* qs[3];
  int M; int K[3]; int tilesPerM; int nGemm; int totB;
  const int* dst; const int* src; const int* etyp;
  const int* offs; const int* rank; u32* sortedST;
  int E; int NR;
};
struct AgArgs {
  const u32* sortedST; const int* offs;
  const float* qd[3]; const float* qs[3]; const float* qr[3];
  const u16* PdAll; const u16* PsAll; const u16* PrAll;
  const float* alphaP; const float* gammaP;
  float* outp; int N; int NR; int E;
};

// ---------- fused prep: fair-interleaved [WC(m=2,1,0) + PR | HIST+RANK] ----------
// PR branch: lanes run along the reduction index i (COALESCED W1 row reads),
// rel rows + bmod staged in LDS, one wave per (r, o-half), butterfly reduce.
__global__ __launch_bounds__(256) void fused_prep(PrepAllArgs a) {
  __shared__ float relL[2][128];
  __shared__ float bmL[128];
  __shared__ float qpr[4];
  int b = blockIdx.x, tid = threadIdx.x;
  long nC = a.nCompute, tot = a.totB;
  int cprev = (int)((long)b * nC / tot);
  int cnext = (int)(((long)b + 1) * nC / tot);
  if (cnext == cprev) {
    // -------- hist + rank --------
    int h = b - cprev;
    int e = h * 256 + tid;
    if (e < a.E) {
      int d = a.dst[e];
      if (d >= 0 && d < a.N) a.rank[e] = atomicAdd(&a.cnt[d], 1);
    }
    return;
  }
  int c = cprev;
  if (c < a.wc0End) {
    // -------- Wc build --------
    int m, loc;
    if (c < a.wc2End)      { m = 2; loc = c; }
    else if (c < a.wc1End) { m = 1; loc = c - a.wc2End; }
    else                   { m = 0; loc = c - a.wc1End; }
    int o = loc & 255, kb = loc >> 8;
    int k = (kb << 8) + tid;
    int K = a.K[m];
    if (k < K) {
      int halfsel = (o >= 128) ? 128 : 0;
      int oo = o & 127;
      const float* W1 = a.W1[m];
      const float* Wm = a.Wmod[m];
      float acc;
      if (Wm == nullptr) {
        acc = W1[oo * 384 + halfsel + k];
      } else {
        acc = 0.f;
        for (int i = 0; i < 128; ++i)
          acc += W1[oo * 384 + halfsel + i] * Wm[i * K + k];
      }
      a.Wc[m][((size_t)(k >> 5) * 256 + o) * 32 + (k & 31)] = f2bf_rne(acc);
    }
  } else {
    // -------- relation prep (coalesced; 2 r per block, 1 wave per (r, o-half)) ----
    int idx = c - a.wc0End;
    int NRpair = (a.NR + 1) >> 1;
    int m = idx / NRpair;
    if (m > 2) return;
    int rp = idx - m * NRpair;
    int r0 = rp * 2;
    {
      int ro = tid >> 7, ii = tid & 127;
      int rr = r0 + ro;
      relL[ro][ii] = (rr < a.NR) ? a.rel[rr * 128 + ii] : 0.f;
    }
    const float* bmod = a.bmod[m];
    if (tid < 128) bmL[tid] = (bmod != nullptr) ? bmod[tid] : 0.f;
    __syncthreads();
    int lane = tid & 63, wv = tid >> 6;
    int rsel = wv >> 1;                 // wave 0,1 -> r0 ; wave 2,3 -> r0+1
    int obase = (wv & 1) * 64;
    int r = r0 + rsel;
    bool rok = (r < a.NR);
    const float* W1 = a.W1[m];
    const float* b1 = a.b1[m];
    const float* w2 = a.w2[m];
    bool hasbm = (bmod != nullptr);
    float qacc = 0.f;
    for (int oo = 0; oo < 64; ++oo) {
      int o = obase + oo;
      const float* row = W1 + o * 384;
      float a2 = row[256 + lane];       // rel slice, i = lane
      float a5 = row[320 + lane];       // rel slice, i = 64+lane
      float s = a2 * relL[rsel][lane] + a5 * relL[rsel][64 + lane];
      if (hasbm) {
        float a0 = row[lane], a1 = row[128 + lane];
        float a3 = row[64 + lane], a4 = row[192 + lane];
        s += (a0 + a1) * bmL[lane] + (a3 + a4) * bmL[64 + lane];
      }
      s = wred_sum(s);                  // all lanes hold sum
      float totv = s + b1[o];
      if (rok && lane == 0)
        a.PrAll[(size_t)r * 384 + m * 128 + o] = f2bf_rne(totv);
      qacc += totv * w2[o];             // lane-uniform
    }
    if (lane == 0) qpr[wv] = qacc;
    __syncthreads();
    if (tid < 2) {
      int rr = r0 + tid;
      if (rr < a.NR) a.qr[m][rr] = sane(qpr[tid * 2] + qpr[tid * 2 + 1]);
    }
  }
}

// 1024-thread single-block exclusive scan of counts → offs
__global__ __launch_bounds__(1024) void scan_k(const int* __restrict__ cnt,
                                               int* __restrict__ offs, int N) {
  __shared__ int sums[1024];
  int t = threadIdx.x;
  int chunk = (N + 1023) >> 10;
  int base = t * chunk;
  int s = 0;
  for (int i = 0; i < chunk; ++i) { int idx = base + i; if (idx < N) s += cnt[idx]; }
  sums[t] = s;
  __syncthreads();
  for (int off = 1; off < 1024; off <<= 1) {
    int v = (t >= off) ? sums[t - off] : 0;
    __syncthreads();
    sums[t] += v;
    __syncthreads();
  }
  int prefix = (t > 0) ? sums[t - 1] : 0;
  for (int i = 0; i < chunk; ++i) {
    int idx = base + i;
    if (idx < N) { offs[idx] = prefix; prefix += cnt[idx]; }
  }
  if (t == 1023) offs[N] = sums[1023];
}

// shared epilogue: interleaved table stores + fused q
__device__ __forceinline__ void gemm_epilogue(const MainArgs& g, int m, int row0,
                                              f32x4 (&acc)[2][4], float (*qpart)[32]) {
  int tid = threadIdx.x;
  int lane = tid & 63, wv = tid >> 6;
  int quad = lane >> 4, l16 = lane & 15;
  int M = g.M;
  const float* w2 = g.w2[m];
  u16* PdAll = g.PdAll;
  u16* PsAll = g.PsAll;
  float w2c[4];
  #pragma unroll
  for (int t = 0; t < 4; ++t) w2c[t] = w2[(wv & 1) * 64 + t * 16 + l16];

  #pragma unroll
  for (int rg = 0; rg < 2; ++rg) {
    float part[4];
    #pragma unroll
    for (int r = 0; r < 4; ++r) {
      int rr = row0 + rg * 16 + quad * 4 + r;
      bool ok = rr < M;
      float qp = 0.f;
      #pragma unroll
      for (int t = 0; t < 4; ++t) {
        int cc = (wv & 1) * 64 + t * 16 + l16;
        if (ok) {
          if (wv < 2) PdAll[(size_t)rr * 384 + m * 128 + cc] = f2bf_rne(acc[rg][t][r]);
          else        PsAll[(size_t)rr * 384 + m * 128 + cc] = f2bf_rne(acc[rg][t][r]);
        }
        qp += acc[rg][t][r] * w2c[t];
      }
      #pragma unroll
      for (int mk = 1; mk < 16; mk <<= 1) qp += __shfl_xor(qp, mk, 64);
      part[r] = qp;
    }
    if (l16 == 0) {
      #pragma unroll
      for (int r = 0; r < 4; ++r) qpart[wv][rg * 16 + quad * 4 + r] = part[r];
    }
  }
  __syncthreads();
  if (tid < 64) {
    int row = tid & 31;
    int half = tid >> 5;
    int rr = row0 + row;
    if (rr < M) {
      if (half == 0) g.qd[m][rr] = sane(qpart[0][row] + qpart[1][row]);
      else           g.qs[m][rr] = sane(qpart[2][row] + qpart[3][row]);
    }
  }
}

// ---------- exact-K gemm: full row in registers (2 half-batches), 1 barrier ----
// LDS [kb][row][k32], XOR 16B-group swizzle phys_g = g ^ (row&3) ^ (kb&3)
// (conflict-free on ds_write_b64 staging and ds_read_b128 frag reads).
// C/D layout (verified): col = lane&15, row = (lane>>4)*4 + reg
template<int NT>
__device__ __forceinline__ void gemm_exact(const MainArgs& g, int m, int tile,
                                           u16* Als, float (*qpart)[32]) {
  constexpr int H = (NT + 1) / 2;
  const int M = g.M;
  int tid = threadIdx.x;
  int lane = tid & 63, wv = tid >> 6;
  int quad = lane >> 4, l16 = lane & 15;
  int row0 = tile * 32;
  int srow = tid >> 3;
  int tk4 = (tid & 7) * 4;
  int srsw = srow & 3;
  int wg = tk4 >> 3;
  int wrem = tk4 & 7;
  int grow = row0 + srow;
  if (grow >= M) grow = M - 1;
  const float* Ag = g.A[m] + (size_t)grow * (NT * 32);

  float4 vreg[H];
  #pragma unroll
  for (int i = 0; i < H; ++i)
    vreg[i] = *reinterpret_cast<const float4*>(Ag + tk4 + i * 32);
  #pragma unroll
  for (int i = 0; i < H; ++i) {
    int gidx = wg ^ srsw ^ (i & 3);
    u32* dp = reinterpret_cast<u32*>(&Als[((i * 32 + srow) * 32) + (gidx << 3) + wrem]);
    dp[0] = packbf2(vreg[i].x, vreg[i].y);
    dp[1] = packbf2(vreg[i].z, vreg[i].w);
  }
  #pragma unroll
  for (int i = H; i < NT; ++i)
    vreg[i - H] = *reinterpret_cast<const float4*>(Ag + tk4 + i * 32);
  #pragma unroll
  for (int i = H; i < NT; ++i) {
    int gidx = wg ^ srsw ^ (i & 3);
    u32* dp = reinterpret_cast<u32*>(&Als[((i * 32 + srow) * 32) + (gidx << 3) + wrem]);
    dp[0] = packbf2(vreg[i - H].x, vreg[i - H].y);
    dp[1] = packbf2(vreg[i - H].z, vreg[i - H].w);
  }
  __syncthreads();

  const u16* Bpg = g.B[m] + (size_t)(wv * 64 + l16) * 32 + quad * 8;
  f32x4 acc[2][4];
  #pragma unroll
  for (int rg = 0; rg < 2; ++rg)
    #pragma unroll
    for (int t = 0; t < 4; ++t) acc[rg][t] = (f32x4){0.f, 0.f, 0.f, 0.f};

  #pragma unroll
  for (int kb = 0; kb < NT; ++kb) {
    const u16* bp = Bpg + (size_t)kb * 8192;
    bf16x8 b0 = *reinterpret_cast<const bf16x8*>(bp);
    bf16x8 b1 = *reinterpret_cast<const bf16x8*>(bp + 512);
    bf16x8 b2 = *reinterpret_cast<const bf16x8*>(bp + 1024);
    bf16x8 b3 = *reinterpret_cast<const bf16x8*>(bp + 1536);
    int gsw = (quad ^ (l16 & 3) ^ (kb & 3)) << 3;
    #pragma unroll
    for (int rg = 0; rg < 2; ++rg) {
      bf16x8 av = *reinterpret_cast<const bf16x8*>(
          &Als[(kb * 32 + rg * 16 + l16) * 32 + gsw]);
      acc[rg][0] = __builtin_amdgcn_mfma_f32_16x16x32_bf16(av, b0, acc[rg][0], 0, 0, 0);
      acc[rg][1] = __builtin_amdgcn_mfma_f32_16x16x32_bf16(av, b1, acc[rg][1], 0, 0, 0);
      acc[rg][2] = __builtin_amdgcn_mfma_f32_16x16x32_bf16(av, b2, acc[rg][2], 0, 0, 0);
      acc[rg][3] = __builtin_amdgcn_mfma_f32_16x16x32_bf16(av, b3, acc[rg][3], 0, 0, 0);
    }
  }
  gemm_epilogue(g, m, row0, acc, qpart);
}

// generic fallback for unexpected K (chunked, 2 barriers/chunk)
__device__ void gemm_generic(const MainArgs& g, int m, int tile,
                             u16* Als, float (*qpart)[32]) {
  const int M = g.M, K = g.K[m];
  int nt = K >> 5;
  int tid = threadIdx.x;
  int lane = tid & 63, wv = tid >> 6;
  int quad = lane >> 4, l16 = lane & 15;
  int row0 = tile * 32;
  int srow = tid >> 3;
  int tk4 = (tid & 7) * 4;
  int srsw = srow & 3;
  int wg = tk4 >> 3;
  int wrem = tk4 & 7;
  int grow = row0 + srow;
  if (grow >= M) grow = M - 1;
  const float* Ag = g.A[m] + (size_t)grow * K;
  const u16* Bpg = g.B[m] + (size_t)(wv * 64 + l16) * 32 + quad * 8;

  f32x4 acc[2][4];
  #pragma unroll
  for (int rg = 0; rg < 2; ++rg)
    #pragma unroll
    for (int t = 0; t < 4; ++t) acc[rg][t] = (f32x4){0.f, 0.f, 0.f, 0.f};

  for (int c0 = 0; c0 < nt; c0 += 24) {
    int kc = nt - c0; if (kc > 24) kc = 24;
    __syncthreads();
    for (int i = 0; i < kc; ++i) {
      int kg = (c0 + i) * 32 + tk4;
      if (kg + 3 < K) {
        float4 v = *reinterpret_cast<const float4*>(Ag + kg);
        int gidx = wg ^ srsw ^ (i & 3);
        u32* dp = reinterpret_cast<u32*>(&Als[((i * 32 + srow) * 32) + (gidx << 3) + wrem]);
        dp[0] = packbf2(v.x, v.y);
        dp[1] = packbf2(v.z, v.w);
      }
    }
    __syncthreads();
    for (int kb = 0; kb < kc; ++kb) {
      const u16* bp = Bpg + (size_t)(c0 + kb) * 8192;
      bf16x8 b0 = *reinterpret_cast<const bf16x8*>(bp);
      bf16x8 b1 = *reinterpret_cast<const bf16x8*>(bp + 512);
      bf16x8 b2 = *reinterpret_cast<const bf16x8*>(bp + 1024);
      bf16x8 b3 = *reinterpret_cast<const bf16x8*>(bp + 1536);
      int gsw = (quad ^ (l16 & 3) ^ (kb & 3)) << 3;
      #pragma unroll
      for (int rg = 0; rg < 2; ++rg) {
        bf16x8 av = *reinterpret_cast<const bf16x8*>(
            &Als[(kb * 32 + rg * 16 + l16) * 32 + gsw]);
        acc[rg][0] = __builtin_amdgcn_mfma_f32_16x16x32_bf16(av, b0, acc[rg][0], 0, 0, 0);
        acc[rg][1] = __builtin_amdgcn_mfma_f32_16x16x32_bf16(av, b1, acc[rg][1], 0, 0, 0);
        acc[rg][2] = __builtin_amdgcn_mfma_f32_16x16x32_bf16(av, b2, acc[rg][2], 0, 0, 0);
        acc[rg][3] = __builtin_amdgcn_mfma_f32_16x16x32_bf16(av, b3, acc[rg][3], 0, 0, 0);
      }
    }
  }
  gemm_epilogue(g, m, row0, acc, qpart);
}

// ---------- fused main: fair-interleaved [GEMM (heavy-first) | SCATTER (no atomics)] ----
__global__ __launch_bounds__(256) void fused_main(MainArgs g) {
  __shared__ __align__(16) u16 Als[24 * 32 * 32];   // 48 KB full-K tile
  __shared__ float qpart[4][32];
  int b = blockIdx.x;
  long nG = g.nGemm, tot = g.totB;
  int gprev = (int)((long)b * nG / tot);
  int gnext = (int)(((long)b + 1) * nG / tot);
  if (gnext == gprev) {
    // -------- scatter (atomic-free: rank precomputed in hist) --------
    int h = b - gprev;
    int e = h * 256 + threadIdx.x;
    if (e < g.E) {
      int d = g.dst[e];
      if (d >= 0 && d < g.M) {
        int pos = g.offs[d] + g.rank[e];
        if (pos >= 0 && pos < g.E) {
          u32 s = (u32)iclamp(g.src[e], g.M);
          u32 t = (u32)iclamp(g.etyp[e], g.NR);
          g.sortedST[pos] = (t << 16) | s;
        }
      }
    }
    return;
  }
  int fb = gprev;
  int tpm = g.tilesPerM;
  int m, tile;
  if (fb < tpm)            { m = 2; tile = fb; }
  else if (fb < 2 * tpm)   { m = 1; tile = fb - tpm; }
  else                     { m = 0; tile = fb - 2 * tpm; }

  int K = g.K[m];
  if (K == 768)      gemm_exact<24>(g, m, tile, Als, qpart);
  else if (K == 512) gemm_exact<16>(g, m, tile, Als, qpart);
  else if (K == 128) gemm_exact<4>(g, m, tile, Als, qpart);
  else               gemm_generic(g, m, tile, Als, qpart);
}

// fused 3-modality ONLINE-softmax aggregate; packed (typ<<16|src); ×4 j-unroll
__global__ __launch_bounds__(256) void aggregate_all(AgArgs a) {
  int n = blockIdx.x * 4 + (threadIdx.x >> 6);
  if (n >= a.N) return;
  int lane = threadIdx.x & 63;
  int E = a.E;
  int eb = a.offs[n], ee = a.offs[n + 1];
  if (eb < 0) eb = 0;
  if (eb > E) eb = E;
  if (ee < eb) ee = eb;
  if (ee > E) ee = E;
  int En = ee - eb;

  float al = a.alphaP[0];
  if (!(al > 0.f && al < 1.f)) al = 0.1f;
  float ga = a.gammaP[0];
  if (!(ga > 0.f && ga < 1.f)) ga = 0.8f;
  float coef[3] = {1.f - al - ga, al, ga};

  float qdn[3];
  #pragma unroll
  for (int m = 0; m < 3; ++m) qdn[m] = sane(a.qd[m][n]);

  const u16* PsAll = a.PsAll;
  const u16* PrAll = a.PrAll;
  int dlo = 2 * lane;

  float rm[3] = {-1e30f, -1e30f, -1e30f};
  float z[3] = {0.f, 0.f, 0.f};
  float a0[3] = {0.f, 0.f, 0.f};
  float a1[3] = {0.f, 0.f, 0.f};
  for (int c0 = 0; c0 < En; c0 += 64) {
    int cn = min(64, En - c0);
    u32 stp = 0;
    float bm[3] = {-1e30f, -1e30f, -1e30f};
    if (lane < cn) {
      stp = a.sortedST[eb + c0 + lane];
      int s = (int)(stp & 0xffffu);
      int t = (int)(stp >> 16);
      #pragma unroll
      for (int m = 0; m < 3; ++m)
        bm[m] = lrelu(qdn[m] + a.qs[m][s] + a.qr[m][t]);
    }
    float wr[3];
    #pragma unroll
    for (int m = 0; m < 3; ++m) {
      float cm = wred_max(bm[m]);
      float nm = fmaxf(rm[m], cm);
      float sc = __expf(fmaxf(rm[m] - nm, -80.f));
      z[m] *= sc; a0[m] *= sc; a1[m] *= sc;
      rm[m] = nm;
      wr[m] = (lane < cn) ? __expf(fmaxf(bm[m] - nm, -80.f)) : 0.f;
      z[m] += wr[m];
    }

    int cnR = (cn + 3) & ~3;
    for (int j = 0; j < cnR; j += 4) {
      u32 stj[4];
      float wj[4][3];
      #pragma unroll
      for (int u = 0; u < 4; ++u) {
        stj[u] = __shfl(stp, j + u, 64);
        wj[u][0] = __shfl(wr[0], j + u, 64);
        wj[u][1] = __shfl(wr[1], j + u, 64);
        wj[u][2] = __shfl(wr[2], j + u, 64);
      }
      u32 pu[4][3], ru[4][3];
      #pragma unroll
      for (int u = 0; u < 4; ++u) {
        const u16* ps = PsAll + (size_t)(stj[u] & 0xffffu) * 384 + dlo;
        const u16* pr = PrAll + (size_t)(stj[u] >> 16) * 384 + dlo;
        #pragma unroll
        for (int m = 0; m < 3; ++m) {
          pu[u][m] = *reinterpret_cast<const u32*>(ps + m * 128);
          ru[u][m] = *reinterpret_cast<const u32*>(pr + m * 128);
        }
      }
      #pragma unroll
      for (int u = 0; u < 4; ++u) {
        #pragma unroll
        for (int m = 0; m < 3; ++m) {
          float ps0 = __uint_as_float(pu[u][m] << 16);
          float ps1 = __uint_as_float(pu[u][m] & 0xffff0000u);
          float pr0 = __uint_as_float(ru[u][m] << 16);
          float pr1 = __uint_as_float(ru[u][m] & 0xffff0000u);
          a0[m] = fmaf(wj[u][m], ps0 + pr0, a0[m]);
          a1[m] = fmaf(wj[u][m], ps1 + pr1, a1[m]);
        }
      }
    }
  }
  #pragma unroll
  for (int m = 0; m < 3; ++m) z[m] = wred_sum(z[m]);

  float o0 = 0.f, o1 = 0.f;
  const u16* pd = a.PdAll + (size_t)n * 384 + dlo;
  #pragma unroll
  for (int m = 0; m < 3; ++m) {
    float h0 = 0.f, h1 = 0.f;
    if (En > 0 && z[m] > 0.f) {
      float rz = 1.f / z[m];
      u32 du = *reinterpret_cast<const u32*>(pd + m * 128);
      float pd0 = __uint_as_float(du << 16), pd1 = __uint_as_float(du & 0xffff0000u);
      h0 = lrelu(pd0 + a0[m] * rz);
      h1 = lrelu(pd1 + a1[m] * rz);
    }
    o0 = fmaf(coef[m], h0, o0);
    o1 = fmaf(coef[m], h1, o1);
  }
  float* op = a.outp + (size_t)n * 128 + dlo;
  op[0] = sane(o0);
  op[1] = sane(o1);
}

extern "C" void kernel_launch(void* const* d_in, const int* in_sizes, int n_in,
                              void* d_out, int out_size, void* d_ws, size_t ws_size,
                              hipStream_t stream) {
  const int* ei        = (const int*)d_in[1];
  const int* et        = (const int*)d_in[2];
  const float* visual  = (const float*)d_in[3];
  const float* textual = (const float*)d_in[4];
  const float* semb    = (const float*)d_in[5];
  const float* relemb  = (const float*)d_in[6];
  const float* W1s = (const float*)d_in[7];
  const float* b1s = (const float*)d_in[8];
  const float* w2s = (const float*)d_in[9];
  const float* W1v = (const float*)d_in[10];
  const float* b1v = (const float*)d_in[11];
  const float* w2v = (const float*)d_in[12];
  const float* W1t = (const float*)d_in[13];
  const float* b1t = (const float*)d_in[14];
  const float* w2t = (const float*)d_in[15];
  const float* Wv  = (const float*)d_in[16];
  const float* bv  = (const float*)d_in[17];
  const float* Wt  = (const float*)d_in[18];
  const float* bt  = (const float*)d_in[19];
  const float* alphaP = (const float*)d_in[20];
  const float* gammaP = (const float*)d_in[21];
  float* outp = (float*)d_out;

  const int E   = in_sizes[2];
  const int N   = in_sizes[5] / DIM;
  const int NR  = in_sizes[6] / DIM;
  const int VIS = in_sizes[3] / N;   // 512
  const int TXT = in_sizes[4] / N;   // 768
  int Ks[3] = {DIM, VIS, TXT};
  const int TPM = (N + 31) / 32;

  const float* W1a[3]   = {W1s, W1v, W1t};
  const float* b1a[3]   = {b1s, b1v, b1t};
  const float* w2a[3]   = {w2s, w2v, w2t};
  const float* Wmoda[3] = {nullptr, Wv, Wt};
  const float* bmoda[3] = {nullptr, bv, bt};
  const float* Amoda[3] = {semb, visual, textual};

  const int* esrc = ei;
  const int* edst = ei + E;
  int egrid = (E + 255) / 256;

  size_t off = 0;
  auto take = [&](size_t bytes) -> size_t {
    size_t o = off;
    off = (off + bytes + 255) & ~(size_t)255;
    return o;
  };
  size_t o_cnt  = take((size_t)N * 4);
  size_t o_rank = take((size_t)E * 4);
  size_t o_offs = take((size_t)(N + 1) * 4);
  size_t o_st   = take((size_t)E * 4);
  size_t o_qdm[3], o_qsm[3], o_qrm[3], o_Wcm[3];
  for (int m = 0; m < 3; ++m) {
    o_qdm[m] = take((size_t)N * 4);
    o_qsm[m] = take((size_t)N * 4);
    o_qrm[m] = take((size_t)NR * 4);
    o_Wcm[m] = take((size_t)256 * Ks[m] * 2);
  }
  size_t o_PrAll = take((size_t)NR * 384 * 2);
  size_t o_PdAll = take((size_t)N * 384 * 2);
  size_t o_PsAll = take((size_t)N * 384 * 2);
  size_t need = off;                           // ~19 MB

  if (ws_size < need) {
    (void)hipMemsetAsync(d_out, 0, (size_t)out_size * 4, stream);  // finite diagnostic
    return;
  }

  char* w = (char*)d_ws;
  int* counts = (int*)(w + o_cnt);
  int* rank   = (int*)(w + o_rank);
  int* offs   = (int*)(w + o_offs);
  u32* sortedST = (u32*)(w + o_st);

  // only counts need zeroing (rank/offs/sortedST fully overwritten)
  (void)hipMemsetAsync(counts, 0, (size_t)N * 4, stream);

  // ---- fused_prep grid: fair-interleave [WC+PR | HIST] ----
  PrepAllArgs pa;
  pa.rel = relemb; pa.NR = NR;
  pa.PrAll = (u16*)(w + o_PrAll);
  pa.dst = edst; pa.cnt = counts; pa.rank = rank; pa.E = E; pa.N = N;
  for (int m = 0; m < 3; ++m) {
    pa.W1[m] = W1a[m]; pa.Wmod[m] = Wmoda[m]; pa.K[m] = Ks[m];
    pa.Wc[m] = (u16*)(w + o_Wcm[m]);
    pa.b1[m] = b1a[m]; pa.bmod[m] = bmoda[m]; pa.w2[m] = w2a[m];
    pa.qr[m] = (float*)(w + o_qrm[m]);
  }
  int NRpair = (NR + 1) / 2;
  int kbm[3];
  for (int m = 0; m < 3; ++m) kbm[m] = (Ks[m] + 255) / 256;
  pa.wc2End   = 256 * kbm[2];
  pa.wc1End   = pa.wc2End + 256 * kbm[1];
  pa.wc0End   = pa.wc1End + 256 * kbm[0];
  pa.nCompute = pa.wc0End + 3 * NRpair;
  pa.totB     = pa.nCompute + egrid;

  // ---- fused_main grid: fair-interleave [GEMM(m=2,1,0) | SCATTER] ----
  MainArgs ga;
  ga.M = N; ga.tilesPerM = TPM; ga.nGemm = 3 * TPM;
  ga.totB = ga.nGemm + egrid;
  ga.PdAll = (u16*)(w + o_PdAll);
  ga.PsAll = (u16*)(w + o_PsAll);
  ga.dst = edst; ga.src = esrc; ga.etyp = et;
  ga.offs = offs; ga.rank = rank; ga.sortedST = sortedST;
  ga.E = E; ga.NR = NR;
  AgArgs aa;
  for (int m = 0; m < 3; ++m) {
    ga.A[m] = Amoda[m]; ga.B[m] = (const u16*)(w + o_Wcm[m]); ga.w2[m] = w2a[m];
    ga.qd[m] = (float*)(w + o_qdm[m]); ga.qs[m] = (float*)(w + o_qsm[m]);
    ga.K[m] = Ks[m];
    aa.qd[m] = (const float*)(w + o_qdm[m]);
    aa.qs[m] = (const float*)(w + o_qsm[m]);
    aa.qr[m] = (const float*)(w + o_qrm[m]);
  }

  aa.PdAll = (const u16*)(w + o_PdAll);
  aa.PsAll = (const u16*)(w + o_PsAll);
  aa.PrAll = (const u16*)(w + o_PrAll);
  aa.sortedST = sortedST; aa.offs = offs;
  aa.alphaP = alphaP; aa.gammaP = gammaP;
  aa.outp = outp; aa.N = N; aa.NR = NR; aa.E = E;

  fused_prep<<<pa.totB, 256, 0, stream>>>(pa);
  scan_k<<<1, 1024, 0, stream>>>(counts, offs, N);
  fused_main<<<ga.totB, 256, 0, stream>>>(ga);
  aggregate_all<<<(N + 3) / 4, 256, 0, stream>>>(aa);
}